// Round 9
// baseline (484.868 us; speedup 1.0000x reference)
//
#include <hip/hip_runtime.h>
#include <hip/hip_bf16.h>
#include <math.h>

typedef __attribute__((ext_vector_type(8))) short bf16x8;
typedef __attribute__((ext_vector_type(4))) float f32x4;

#define N_TOK 1024
#define HID   2048
#define NEXP  16
#define NE2   18      // 16 routed + 2 shared pseudo-experts
#define INTER 1024
#define TOPK  6
#define CAP   1024

__device__ __forceinline__ unsigned short f2bf(float f) {
  unsigned u = __builtin_bit_cast(unsigned, f);
  u += 0x7fffu + ((u >> 16) & 1u);          // round-to-nearest-even
  return (unsigned short)(u >> 16);
}
__device__ __forceinline__ float b2f(short s) {
  unsigned u = ((unsigned)(unsigned short)s) << 16;
  return __builtin_bit_cast(float, u);
}
__device__ __forceinline__ void gll16(const void* g, void* l) {
  __builtin_amdgcn_global_load_lds(
      (const __attribute__((address_space(1))) unsigned int*)g,
      (__attribute__((address_space(3))) unsigned int*)l, 16, 0, 0);
}

// ---------------------------------------------------------------- router ----
__global__ __launch_bounds__(256) void router_k(
    const float* __restrict__ x, const float* __restrict__ gw,
    const float* __restrict__ gb, int* __restrict__ counts,
    int* __restrict__ tok_list, int* __restrict__ meta,
    float* __restrict__ pwt, unsigned short* __restrict__ x_bf)
{
  const int t   = blockIdx.x;
  const int tid = threadIdx.x;
  __shared__ float xrow[HID];
  __shared__ float logits[NEXP];

  for (int i = tid; i < HID; i += 256) {
    float v = x[(size_t)t * HID + i];
    xrow[i] = v;
    x_bf[(size_t)t * HID + i] = f2bf(v);
  }
  __syncthreads();

  const int w = tid >> 6, lane = tid & 63;
  for (int s = 0; s < 4; ++s) {
    int e = w * 4 + s;
    const float* g = gw + (size_t)e * HID;
    float p = 0.f;
    for (int i = lane; i < HID; i += 64) p += xrow[i] * g[i];
    for (int off = 32; off; off >>= 1) p += __shfl_down(p, off);
    if (lane == 0) logits[e] = p;
  }
  __syncthreads();

  if (tid == 0) {
    float sc[NEXP], scorr[NEXP];
    for (int e = 0; e < NEXP; ++e) {
      float s1 = 1.f / (1.f + expf(-logits[e]));
      sc[e] = s1; scorr[e] = s1 + gb[e];
    }
    float gs[4];
    for (int g = 0; g < 4; ++g) {
      float m1 = -1e30f, m2 = -1e30f;
      for (int j = 0; j < 4; ++j) {
        float v = scorr[g * 4 + j];
        if (v > m1) { m2 = m1; m1 = v; } else if (v > m2) m2 = v;
      }
      gs[g] = m1 + m2;
    }
    int g1 = 0;
    for (int g = 1; g < 4; ++g) if (gs[g] > gs[g1]) g1 = g;
    int g2 = -1;
    for (int g = 0; g < 4; ++g) { if (g == g1) continue; if (g2 < 0 || gs[g] > gs[g2]) g2 = g; }

    bool taken[NEXP];
    for (int e = 0; e < NEXP; ++e) taken[e] = false;
    int ids[TOPK]; float wv[TOPK]; float wsum = 0.f;
    for (int k = 0; k < TOPK; ++k) {
      int best = -1; float bv = -1e30f;
      for (int e = 0; e < NEXP; ++e) {
        int grp = e >> 2;
        if (grp != g1 && grp != g2) continue;
        if (taken[e]) continue;
        if (scorr[e] > bv) { bv = scorr[e]; best = e; }
      }
      taken[best] = true; ids[k] = best; wv[k] = sc[best]; wsum += sc[best];
    }
    float inv = 2.5f / wsum;
    for (int k = 0; k < TOPK; ++k) {
      int e = ids[k];
      int slot = atomicAdd(&counts[e], 1);
      tok_list[e * CAP + slot] = t;
      meta[t * TOPK + k] = (e << 16) | slot;
      pwt[t * TOPK + k] = wv[k] * inv;
    }
  }
}

// ----------------------------------------------- weight convert+transpose ---
// v2: per-thread 4x4 in-register micro-transpose; vector LDS ops both sides.
__global__ __launch_bounds__(256) void t_gu_k(
    const float* __restrict__ wgu, const float* __restrict__ sgu,
    unsigned short* __restrict__ dst)
{
  const int z = blockIdx.z;
  const int n0 = blockIdx.x * 64, k0 = blockIdx.y * 64;
  const float* src; int ld; int cb;
  if (z < 16) { src = wgu + (size_t)z * HID * (2 * INTER); ld = 2 * INTER; cb = n0; }
  else { int j = z - 16; src = sgu; ld = 4096;
         cb = (n0 < 1024) ? j * 1024 + n0 : 1024 * j + 1024 + n0; }
  __shared__ __align__(16) unsigned short t2[64][72];   // 144 B row stride
  const int tid = threadIdx.x;
  const int kb = tid >> 4, nb = tid & 15;               // 4x4 block
  unsigned short h[4][4];
  #pragma unroll
  for (int j = 0; j < 4; ++j) {
    float4 f = *(const float4*)(src + (size_t)(k0 + kb * 4 + j) * ld + cb + nb * 4);
    h[j][0] = f2bf(f.x); h[j][1] = f2bf(f.y); h[j][2] = f2bf(f.z); h[j][3] = f2bf(f.w);
  }
  #pragma unroll
  for (int i = 0; i < 4; ++i) {
    int rr = nb * 4 + i;
    unsigned lo  = h[0][i] | ((unsigned)h[1][i] << 16);
    unsigned hi2 = h[2][i] | ((unsigned)h[3][i] << 16);
    unsigned long long v = (unsigned long long)lo | ((unsigned long long)hi2 << 32);
    *(unsigned long long*)((char*)t2 + rr * 144 + ((kb * 8) ^ ((rr & 7) << 4))) = v;
  }
  __syncthreads();
  unsigned short* d = dst + (size_t)z * HID * (2 * INTER);
  #pragma unroll
  for (int i = 0; i < 2; ++i) {
    int c = tid + 256 * i;                 // 512 chunks of 16 B
    int nl = c >> 3, s = c & 7;
    uint4 v = *(const uint4*)((const char*)t2 + nl * 144 + ((s * 16) ^ ((nl & 7) << 4)));
    *(uint4*)(d + (size_t)(n0 + nl) * HID + k0 + s * 8) = v;
  }
}

__global__ __launch_bounds__(256) void t_d_k(
    const float* __restrict__ wd, const float* __restrict__ sd,
    unsigned short* __restrict__ dst)
{
  const int z = blockIdx.z;
  const int n0 = blockIdx.x * 64, k0 = blockIdx.y * 64;
  const float* src = (z < 16) ? wd + (size_t)z * INTER * HID
                              : sd + (size_t)(z - 16) * INTER * HID;
  __shared__ __align__(16) unsigned short t2[64][72];
  const int tid = threadIdx.x;
  const int kb = tid >> 4, nb = tid & 15;
  unsigned short h[4][4];
  #pragma unroll
  for (int j = 0; j < 4; ++j) {
    float4 f = *(const float4*)(src + (size_t)(k0 + kb * 4 + j) * HID + n0 + nb * 4);
    h[j][0] = f2bf(f.x); h[j][1] = f2bf(f.y); h[j][2] = f2bf(f.z); h[j][3] = f2bf(f.w);
  }
  #pragma unroll
  for (int i = 0; i < 4; ++i) {
    int rr = nb * 4 + i;
    unsigned lo  = h[0][i] | ((unsigned)h[1][i] << 16);
    unsigned hi2 = h[2][i] | ((unsigned)h[3][i] << 16);
    unsigned long long v = (unsigned long long)lo | ((unsigned long long)hi2 << 32);
    *(unsigned long long*)((char*)t2 + rr * 144 + ((kb * 8) ^ ((rr & 7) << 4))) = v;
  }
  __syncthreads();
  unsigned short* d = dst + (size_t)z * HID * INTER;
  #pragma unroll
  for (int i = 0; i < 2; ++i) {
    int c = tid + 256 * i;
    int nl = c >> 3, s = c & 7;
    uint4 v = *(const uint4*)((const char*)t2 + nl * 144 + ((s * 16) ^ ((nl & 7) << 4)));
    *(uint4*)(d + (size_t)(n0 + nl) * INTER + k0 + s * 8) = v;
  }
}

// -------------------- grouped bf16 GEMM: BM=128 x Brows=256, BK=64, 4 waves -
// acc[4][8] (64 MFMA/wave/tile = 310cyc of cover). LDS: A single 16 KiB +
// B double-buffered 2x32 KiB = 80 KiB -> 2 blocks/CU. Per tile: issue B(t+1)
// glls BEFORE compute (620 cyc cover), compute, s_barrier, issue A(t+1)
// (L2-hot activations), vmcnt(0), s_barrier. Both operands via gll16 w=16
// (linear dest, inverse-swizzled source); ds_read_b128 with (r&7)<<4 XOR.
// MODE 0: gemm1 — gather A via tok_list (e<16); B rows 0..127 = g (n0+r),
//         128..255 = u (1024+n0+r-128); swiglu -> bf16 (128 cols/block).
// MODE 1: gemm2 — plain bf16 store (256 cols/block).
template<int MODE>
__global__ __launch_bounds__(256, 2) void gemm_bf16_k(
    const unsigned short* __restrict__ A, int lda, size_t a_estride,
    const unsigned short* __restrict__ Wt, int K, size_t w_estride,
    const int* __restrict__ counts, const int* __restrict__ tok_list,
    unsigned short* __restrict__ outb, int out_ld, size_t out_estride)
{
  const int e  = blockIdx.z;
  const int m0 = blockIdx.y * 128;
  const int M  = (e < 16) ? counts[e] : N_TOK;
  if (m0 >= M) return;
  const int n0 = blockIdx.x * (MODE == 0 ? 128 : 256);

  __shared__ __align__(16) unsigned short Al[128 * 64];       // 16 KiB
  __shared__ __align__(16) unsigned short Bl[2][256 * 64];    // 2 x 32 KiB

  const int tid = threadIdx.x, lane = tid & 63, wid = tid >> 6;
  const int wm = wid >> 1, wn = wid & 1, l15 = lane & 15, hi = lane >> 4;

  const unsigned short* Ap = A + (size_t)e * a_estride;
  const unsigned short* Wp = Wt + (size_t)e * w_estride;

  // ---- A staging: 4 chunks of 16B/thread; rows gathered (MODE 0, e<16) ----
  const int r0 = tid >> 3, s0 = tid & 7, sl = s0 ^ (r0 & 7);
  const unsigned short* asrc[4]; int aoff[4];
  #pragma unroll
  for (int i = 0; i < 4; ++i) {
    int r = r0 + 32 * i;                  // 0..127
    int slot = m0 + r;
    int row;
    if (MODE == 0) row = (e < 16) ? ((slot < M) ? tok_list[e * CAP + slot] : 0) : slot;
    else           row = slot;
    asrc[i] = Ap + (size_t)row * lda + sl * 8;
    aoff[i] = (tid + 256 * i) * 16;
  }
  // ---- B staging: 8 chunks of 16B/thread; rows r = r0 + 32*i (0..255) ----
  const unsigned short* bpg;   // rows 0..127  (g for MODE0; all for MODE1)
  const unsigned short* bpu;   // rows 128..255 (u for MODE0)
  if (MODE == 0) {
    bpg = Wp + (size_t)(n0 + r0) * K + sl * 8;
    bpu = Wp + (size_t)(1024 + n0 + r0) * K + sl * 8;
  } else {
    bpg = Wp + (size_t)(n0 + r0) * K + sl * 8;
    bpu = bpg + (size_t)128 * K;
  }
  const size_t bstep = (size_t)32 * K;

  int bn[8];
  #pragma unroll
  for (int ni = 0; ni < 8; ++ni) {
    if (MODE == 0) bn[ni] = (ni < 4) ? (wn * 64 + ni * 16) : (128 + wn * 64 + (ni - 4) * 16);
    else           bn[ni] = wn * 128 + ni * 16;
  }

  f32x4 acc[4][8];
  #pragma unroll
  for (int a0 = 0; a0 < 4; ++a0)
    #pragma unroll
    for (int b0 = 0; b0 < 8; ++b0) acc[a0][b0] = (f32x4){0.f, 0.f, 0.f, 0.f};

  #define ISSUE_B(buf, kt)                                                  \
    _Pragma("unroll")                                                       \
    for (int i = 0; i < 4; ++i)                                             \
      gll16(bpg + bstep * i + (kt), (char*)(buf) + (tid + 256 * i) * 16);   \
    _Pragma("unroll")                                                       \
    for (int i = 0; i < 4; ++i)                                             \
      gll16(bpu + bstep * i + (kt), (char*)(buf) + (tid + 256 * (i + 4)) * 16);
  #define ISSUE_A(kt)                                                       \
    _Pragma("unroll")                                                       \
    for (int i = 0; i < 4; ++i) gll16(asrc[i] + (kt), (char*)Al + aoff[i]);
  #define COMPUTE(Bb)                                                       \
    _Pragma("unroll")                                                       \
    for (int kk = 0; kk < 64; kk += 32) {                                   \
      bf16x8 af[4], bv[8];                                                  \
      _Pragma("unroll")                                                     \
      for (int mi = 0; mi < 4; ++mi) {                                      \
        int r = wm * 64 + mi * 16 + l15;                                    \
        int off = (r * 128 + (kk + hi * 8) * 2) ^ ((r & 7) << 4);           \
        af[mi] = *(const bf16x8*)((const char*)Al + off);                   \
      }                                                                     \
      _Pragma("unroll")                                                     \
      for (int ni = 0; ni < 8; ++ni) {                                      \
        int r = bn[ni] + l15;                                               \
        int off = (r * 128 + (kk + hi * 8) * 2) ^ ((r & 7) << 4);           \
        bv[ni] = *(const bf16x8*)((const char*)(Bb) + off);                 \
      }                                                                     \
      _Pragma("unroll")                                                     \
      for (int mi = 0; mi < 4; ++mi)                                        \
        _Pragma("unroll")                                                   \
        for (int ni = 0; ni < 8; ++ni)                                      \
          acc[mi][ni] = __builtin_amdgcn_mfma_f32_16x16x32_bf16(            \
              af[mi], bv[ni], acc[mi][ni], 0, 0, 0);                        \
    }

  const int nt = K >> 6;
  // ---- prologue: stage tile 0 ----
  ISSUE_B(Bl[0], 0)
  ISSUE_A(0)
  asm volatile("s_waitcnt vmcnt(0)" ::: "memory");
  __builtin_amdgcn_s_barrier();

  int p = 0;
  for (int t = 0; t < nt; ++t) {
    const bool pf = (t + 1 < nt);
    if (pf) { ISSUE_B(Bl[p ^ 1], (t + 1) << 6) }   // flies under compute
    COMPUTE(Bl[p])
    __builtin_amdgcn_s_barrier();                  // all waves done reading Al/Bl[p]
    if (pf) {
      ISSUE_A((t + 1) << 6)                        // A from L2/L3-hot acts
      asm volatile("s_waitcnt vmcnt(0)" ::: "memory");
      __builtin_amdgcn_s_barrier();
    }
    p ^= 1;
  }
  #undef ISSUE_B
  #undef ISSUE_A
  #undef COMPUTE

  // ---- epilogue ----  C/D: col=lane&15, row=(lane>>4)*4+reg
  const int rbase = hi * 4;
  if (MODE == 0) {
    #pragma unroll
    for (int mi = 0; mi < 4; ++mi)
      #pragma unroll
      for (int rr = 0; rr < 4; ++rr) {
        int slot = m0 + wm * 64 + mi * 16 + rbase + rr;
        if (slot >= M) continue;
        #pragma unroll
        for (int ni = 0; ni < 4; ++ni) {
          float g = acc[mi][ni][rr], u = acc[mi][ni + 4][rr];
          float sv = g / (1.f + expf(-g)) * u;
          int col = n0 + wn * 64 + ni * 16 + l15;
          outb[(size_t)e * out_estride + (size_t)slot * out_ld + col] = f2bf(sv);
        }
      }
  } else {
    #pragma unroll
    for (int mi = 0; mi < 4; ++mi)
      #pragma unroll
      for (int rr = 0; rr < 4; ++rr) {
        int slot = m0 + wm * 64 + mi * 16 + rbase + rr;
        if (slot >= M) continue;
        unsigned short* row = outb + (size_t)e * out_estride + (size_t)slot * out_ld;
        #pragma unroll
        for (int ni = 0; ni < 8; ++ni)
          row[n0 + bn[ni] + l15] = f2bf(acc[mi][ni][rr]);
      }
  }
}

// ---------------------------------------------------------------- combine ---
// out[t] = sum_k pw[t,k]*y[e_k][slot_k] + y[16][t] + y[17][t]
__global__ __launch_bounds__(256) void combine_k(
    const unsigned short* __restrict__ ybuf, const int* __restrict__ meta,
    const float* __restrict__ pwt, float* __restrict__ out)
{
  const int t = blockIdx.x;
  const int c0 = threadIdx.x * 8;
  float acc[8];
  {
    bf16x8 v0 = *(const bf16x8*)(ybuf + ((size_t)16 * CAP + t) * HID + c0);
    bf16x8 v1 = *(const bf16x8*)(ybuf + ((size_t)17 * CAP + t) * HID + c0);
    #pragma unroll
    for (int j = 0; j < 8; ++j) acc[j] = b2f(v0[j]) + b2f(v1[j]);
  }
  #pragma unroll
  for (int k = 0; k < TOPK; ++k) {
    int m = meta[t * TOPK + k];
    float w = pwt[t * TOPK + k];
    int e = m >> 16, s = m & 0xffff;
    bf16x8 v = *(const bf16x8*)(ybuf + ((size_t)e * CAP + s) * HID + c0);
    #pragma unroll
    for (int j = 0; j < 8; ++j) acc[j] += w * b2f(v[j]);
  }
  float4* o = (float4*)(out + (size_t)t * HID + c0);
  o[0] = make_float4(acc[0], acc[1], acc[2], acc[3]);
  o[1] = make_float4(acc[4], acc[5], acc[6], acc[7]);
}

// --------------------------------------------------------------- launcher ---
extern "C" void kernel_launch(void* const* d_in, const int* in_sizes, int n_in,
                              void* d_out, int out_size, void* d_ws, size_t ws_size,
                              hipStream_t stream) {
  const float* x   = (const float*)d_in[0];
  const float* gw  = (const float*)d_in[1];
  const float* gb  = (const float*)d_in[2];
  const float* wgu = (const float*)d_in[3];
  const float* wd  = (const float*)d_in[4];
  const float* sgu = (const float*)d_in[5];
  const float* sd  = (const float*)d_in[6];
  float* out = (float*)d_out;

  char* ws = (char*)d_ws;
  int*   counts   = (int*)ws;                              // 256 B
  int*   tok_list = (int*)(ws + 256);                      // 64 KB
  int*   meta     = (int*)(ws + 256 + 65536);              // 24 KB
  float* pwt      = (float*)(ws + 256 + 65536 + 24576);    // 24 KB
  unsigned short* x_bf  = (unsigned short*)(ws + 128 * 1024);          // 4 MiB
  unsigned short* act   = x_bf + (size_t)N_TOK * HID;                  // 36 MiB
  unsigned short* ybuf  = act + (size_t)NE2 * CAP * INTER;             // 72 MiB
  unsigned short* wt_gu = ybuf + (size_t)NE2 * CAP * HID;              // 144 MiB
  unsigned short* wt_d  = wt_gu + (size_t)NE2 * HID * 2 * INTER;       // 72 MiB
  const size_t need = (size_t)((char*)(wt_d + (size_t)NE2 * HID * INTER) - ws);
  if (ws_size < need) return;   // ws measured at 1 GiB; need ~328 MiB

  hipMemsetAsync(counts, 0, 256, stream);
  router_k<<<N_TOK, 256, 0, stream>>>(x, gw, gb, counts, tok_list, meta, pwt, x_bf);

  t_gu_k<<<dim3(2 * INTER / 64, HID / 64, NE2), 256, 0, stream>>>(wgu, sgu, wt_gu);
  t_d_k<<<dim3(HID / 64, INTER / 64, NE2), 256, 0, stream>>>(wd, sd, wt_d);

  // gemm1: [18] gather(x)[M,2048] @ wt_gu[e][n][k] -> swiglu -> act[e][M,1024]
  gemm_bf16_k<0><<<dim3(INTER / 128, CAP / 128, NE2), 256, 0, stream>>>(
      x_bf, HID, 0, wt_gu, HID, (size_t)HID * 2 * INTER, counts, tok_list,
      act, INTER, (size_t)CAP * INTER);
  // gemm2: [18] act[e][M,1024] @ wt_d[e][n][k] -> ybuf[e][M,2048] (bf16)
  gemm_bf16_k<1><<<dim3(HID / 256, CAP / 128, NE2), 256, 0, stream>>>(
      act, INTER, (size_t)CAP * INTER, wt_d, INTER, (size_t)HID * INTER, counts, nullptr,
      ybuf, HID, (size_t)CAP * HID);

  combine_k<<<N_TOK, 256, 0, stream>>>(ybuf, meta, pwt, out);
}

// Round 10
// 448.936 us; speedup vs baseline: 1.0800x; 1.0800x over previous
//
#include <hip/hip_runtime.h>
#include <hip/hip_bf16.h>
#include <math.h>

typedef __attribute__((ext_vector_type(8))) short bf16x8;
typedef __attribute__((ext_vector_type(4))) float f32x4;

#define N_TOK 1024
#define HID   2048
#define NEXP  16
#define NE2   18      // 16 routed + 2 shared pseudo-experts
#define INTER 1024
#define TOPK  6
#define CAP   1024

__device__ __forceinline__ unsigned short f2bf(float f) {
  unsigned u = __builtin_bit_cast(unsigned, f);
  u += 0x7fffu + ((u >> 16) & 1u);          // round-to-nearest-even
  return (unsigned short)(u >> 16);
}
__device__ __forceinline__ float b2f(short s) {
  unsigned u = ((unsigned)(unsigned short)s) << 16;
  return __builtin_bit_cast(float, u);
}
__device__ __forceinline__ void gll16(const void* g, void* l) {
  __builtin_amdgcn_global_load_lds(
      (const __attribute__((address_space(1))) unsigned int*)g,
      (__attribute__((address_space(3))) unsigned int*)l, 16, 0, 0);
}

// ---------------------------------------------------------------- router ----
__global__ __launch_bounds__(256) void router_k(
    const float* __restrict__ x, const float* __restrict__ gw,
    const float* __restrict__ gb, int* __restrict__ counts,
    int* __restrict__ tok_list, int* __restrict__ meta,
    float* __restrict__ pwt, unsigned short* __restrict__ x_bf)
{
  const int t   = blockIdx.x;
  const int tid = threadIdx.x;
  __shared__ float xrow[HID];
  __shared__ float logits[NEXP];

  for (int i = tid; i < HID; i += 256) {
    float v = x[(size_t)t * HID + i];
    xrow[i] = v;
    x_bf[(size_t)t * HID + i] = f2bf(v);
  }
  __syncthreads();

  const int w = tid >> 6, lane = tid & 63;
  for (int s = 0; s < 4; ++s) {
    int e = w * 4 + s;
    const float* g = gw + (size_t)e * HID;
    float p = 0.f;
    for (int i = lane; i < HID; i += 64) p += xrow[i] * g[i];
    for (int off = 32; off; off >>= 1) p += __shfl_down(p, off);
    if (lane == 0) logits[e] = p;
  }
  __syncthreads();

  if (tid == 0) {
    float sc[NEXP], scorr[NEXP];
    for (int e = 0; e < NEXP; ++e) {
      float s1 = 1.f / (1.f + expf(-logits[e]));
      sc[e] = s1; scorr[e] = s1 + gb[e];
    }
    float gs[4];
    for (int g = 0; g < 4; ++g) {
      float m1 = -1e30f, m2 = -1e30f;
      for (int j = 0; j < 4; ++j) {
        float v = scorr[g * 4 + j];
        if (v > m1) { m2 = m1; m1 = v; } else if (v > m2) m2 = v;
      }
      gs[g] = m1 + m2;
    }
    int g1 = 0;
    for (int g = 1; g < 4; ++g) if (gs[g] > gs[g1]) g1 = g;
    int g2 = -1;
    for (int g = 0; g < 4; ++g) { if (g == g1) continue; if (g2 < 0 || gs[g] > gs[g2]) g2 = g; }

    bool taken[NEXP];
    for (int e = 0; e < NEXP; ++e) taken[e] = false;
    int ids[TOPK]; float wv[TOPK]; float wsum = 0.f;
    for (int k = 0; k < TOPK; ++k) {
      int best = -1; float bv = -1e30f;
      for (int e = 0; e < NEXP; ++e) {
        int grp = e >> 2;
        if (grp != g1 && grp != g2) continue;
        if (taken[e]) continue;
        if (scorr[e] > bv) { bv = scorr[e]; best = e; }
      }
      taken[best] = true; ids[k] = best; wv[k] = sc[best]; wsum += sc[best];
    }
    float inv = 2.5f / wsum;
    for (int k = 0; k < TOPK; ++k) {
      int e = ids[k];
      int slot = atomicAdd(&counts[e], 1);
      tok_list[e * CAP + slot] = t;
      meta[t * TOPK + k] = (e << 16) | slot;
      pwt[t * TOPK + k] = wv[k] * inv;
    }
  }
}

// ----------------------------------------------- weight convert+transpose ---
// v2: per-thread 4x4 in-register micro-transpose; vector LDS ops both sides.
__global__ __launch_bounds__(256) void t_gu_k(
    const float* __restrict__ wgu, const float* __restrict__ sgu,
    unsigned short* __restrict__ dst)
{
  const int z = blockIdx.z;
  const int n0 = blockIdx.x * 64, k0 = blockIdx.y * 64;
  const float* src; int ld; int cb;
  if (z < 16) { src = wgu + (size_t)z * HID * (2 * INTER); ld = 2 * INTER; cb = n0; }
  else { int j = z - 16; src = sgu; ld = 4096;
         cb = (n0 < 1024) ? j * 1024 + n0 : 1024 * j + 1024 + n0; }
  __shared__ __align__(16) unsigned short t2[64][72];   // 144 B row stride
  const int tid = threadIdx.x;
  const int kb = tid >> 4, nb = tid & 15;               // 4x4 block
  unsigned short h[4][4];
  #pragma unroll
  for (int j = 0; j < 4; ++j) {
    float4 f = *(const float4*)(src + (size_t)(k0 + kb * 4 + j) * ld + cb + nb * 4);
    h[j][0] = f2bf(f.x); h[j][1] = f2bf(f.y); h[j][2] = f2bf(f.z); h[j][3] = f2bf(f.w);
  }
  #pragma unroll
  for (int i = 0; i < 4; ++i) {
    int rr = nb * 4 + i;
    unsigned lo  = h[0][i] | ((unsigned)h[1][i] << 16);
    unsigned hi2 = h[2][i] | ((unsigned)h[3][i] << 16);
    unsigned long long v = (unsigned long long)lo | ((unsigned long long)hi2 << 32);
    *(unsigned long long*)((char*)t2 + rr * 144 + ((kb * 8) ^ ((rr & 7) << 4))) = v;
  }
  __syncthreads();
  unsigned short* d = dst + (size_t)z * HID * (2 * INTER);
  #pragma unroll
  for (int i = 0; i < 2; ++i) {
    int c = tid + 256 * i;                 // 512 chunks of 16 B
    int nl = c >> 3, s = c & 7;
    uint4 v = *(const uint4*)((const char*)t2 + nl * 144 + ((s * 16) ^ ((nl & 7) << 4)));
    *(uint4*)(d + (size_t)(n0 + nl) * HID + k0 + s * 8) = v;
  }
}

__global__ __launch_bounds__(256) void t_d_k(
    const float* __restrict__ wd, const float* __restrict__ sd,
    unsigned short* __restrict__ dst)
{
  const int z = blockIdx.z;
  const int n0 = blockIdx.x * 64, k0 = blockIdx.y * 64;
  const float* src = (z < 16) ? wd + (size_t)z * INTER * HID
                              : sd + (size_t)(z - 16) * INTER * HID;
  __shared__ __align__(16) unsigned short t2[64][72];
  const int tid = threadIdx.x;
  const int kb = tid >> 4, nb = tid & 15;
  unsigned short h[4][4];
  #pragma unroll
  for (int j = 0; j < 4; ++j) {
    float4 f = *(const float4*)(src + (size_t)(k0 + kb * 4 + j) * HID + n0 + nb * 4);
    h[j][0] = f2bf(f.x); h[j][1] = f2bf(f.y); h[j][2] = f2bf(f.z); h[j][3] = f2bf(f.w);
  }
  #pragma unroll
  for (int i = 0; i < 4; ++i) {
    int rr = nb * 4 + i;
    unsigned lo  = h[0][i] | ((unsigned)h[1][i] << 16);
    unsigned hi2 = h[2][i] | ((unsigned)h[3][i] << 16);
    unsigned long long v = (unsigned long long)lo | ((unsigned long long)hi2 << 32);
    *(unsigned long long*)((char*)t2 + rr * 144 + ((kb * 8) ^ ((rr & 7) << 4))) = v;
  }
  __syncthreads();
  unsigned short* d = dst + (size_t)z * HID * INTER;
  #pragma unroll
  for (int i = 0; i < 2; ++i) {
    int c = tid + 256 * i;
    int nl = c >> 3, s = c & 7;
    uint4 v = *(const uint4*)((const char*)t2 + nl * 144 + ((s * 16) ^ ((nl & 7) << 4)));
    *(uint4*)(d + (size_t)(n0 + nl) * INTER + k0 + s * 8) = v;
  }
}

// --------------------------------------------------- grouped bf16 GEMM ------
// R3 structure (128x128 tile, BK=64, 4 waves 2x2, gll16 both operands,
// (r&7)<<4 read swizzle) + DOUBLE-BUFFERED LDS (64 KiB): per tile, issue all
// 8 glls of tile t+1 BEFORE compute(t); drain with vmcnt(0) AFTER compute
// (compute covers most of the latency); one barrier per tile. No XCD remap.
// MODE 0: gemm1 — gather A rows via tok_list (e<16) or identity (shared);
//         B rows r<64 = g (n0+r), r>=64 = u (1024+n0+r-64); swiglu -> bf16.
// MODE 1: gemm2 — plain bf16 store (BN=128).
template<int MODE>
__global__ __launch_bounds__(256) void gemm_bf16_k(
    const unsigned short* __restrict__ A, int lda, size_t a_estride,
    const unsigned short* __restrict__ Wt, int K, size_t w_estride,
    const int* __restrict__ counts, const int* __restrict__ tok_list,
    unsigned short* __restrict__ outb, int out_ld, size_t out_estride)
{
  const int e  = blockIdx.z;
  const int m0 = blockIdx.y * 128;
  const int M  = (e < 16) ? counts[e] : N_TOK;
  if (m0 >= M) return;
  const int n0 = blockIdx.x * (MODE == 0 ? 64 : 128);

  __shared__ __align__(16) unsigned short Al[2][128 * 64];   // 2 x 16 KB
  __shared__ __align__(16) unsigned short Bl[2][128 * 64];   // 2 x 16 KB

  const int tid = threadIdx.x, lane = tid & 63, wid = tid >> 6;
  const int wm = wid >> 1, wn = wid & 1, l15 = lane & 15, hi = lane >> 4;

  const unsigned short* Ap = A + (size_t)e * a_estride;
  const unsigned short* Wp = Wt + (size_t)e * w_estride;

  // staging descriptors (constant over K-loop)
  const unsigned short* asrc[4]; int soff[4];
  const unsigned short* bsrc[4];
  #pragma unroll
  for (int i = 0; i < 4; ++i) {
    int c = tid + 256 * i;                 // 0..1023, 16B each
    int r = c >> 3, s = c & 7, sl = s ^ (r & 7);
    int slot = m0 + r;
    int row;
    if (MODE == 0) row = (e < 16) ? ((slot < M) ? tok_list[e * CAP + slot] : 0) : slot;
    else           row = slot;
    asrc[i] = Ap + (size_t)row * lda + sl * 8;
    soff[i] = c * 16;
    int nrow = (MODE == 0) ? ((r < 64) ? n0 + r : 1024 + n0 + (r - 64)) : (n0 + r);
    bsrc[i] = Wp + (size_t)nrow * K + sl * 8;
  }

  int bn[4];
  if (MODE == 0) { bn[0] = wn*32; bn[1] = wn*32+16; bn[2] = 64+wn*32; bn[3] = 80+wn*32; }
  else           { bn[0] = wn*64; bn[1] = wn*64+16; bn[2] = wn*64+32; bn[3] = wn*64+48; }

  f32x4 acc[4][4];
  #pragma unroll
  for (int a0 = 0; a0 < 4; ++a0)
    #pragma unroll
    for (int b0 = 0; b0 < 4; ++b0) acc[a0][b0] = (f32x4){0.f, 0.f, 0.f, 0.f};

  #define ISSUE(buf_i, kt)                                                  \
    _Pragma("unroll")                                                       \
    for (int i = 0; i < 4; ++i)                                             \
      gll16(bsrc[i] + (kt), (char*)Bl[buf_i] + soff[i]);                    \
    _Pragma("unroll")                                                       \
    for (int i = 0; i < 4; ++i)                                             \
      gll16(asrc[i] + (kt), (char*)Al[buf_i] + soff[i]);
  #define COMPUTE(buf_i)                                                    \
    _Pragma("unroll")                                                       \
    for (int kk = 0; kk < 64; kk += 32) {                                   \
      bf16x8 af[4], bv[4];                                                  \
      _Pragma("unroll")                                                     \
      for (int mi = 0; mi < 4; ++mi) {                                      \
        int r = wm * 64 + mi * 16 + l15;                                    \
        int off = (r * 128 + (kk + hi * 8) * 2) ^ ((r & 7) << 4);           \
        af[mi] = *(const bf16x8*)((const char*)Al[buf_i] + off);            \
      }                                                                     \
      _Pragma("unroll")                                                     \
      for (int ni = 0; ni < 4; ++ni) {                                      \
        int r = bn[ni] + l15;                                               \
        int off = (r * 128 + (kk + hi * 8) * 2) ^ ((r & 7) << 4);           \
        bv[ni] = *(const bf16x8*)((const char*)Bl[buf_i] + off);            \
      }                                                                     \
      _Pragma("unroll")                                                     \
      for (int mi = 0; mi < 4; ++mi)                                        \
        _Pragma("unroll")                                                   \
        for (int ni = 0; ni < 4; ++ni)                                      \
          acc[mi][ni] = __builtin_amdgcn_mfma_f32_16x16x32_bf16(            \
              af[mi], bv[ni], acc[mi][ni], 0, 0, 0);                        \
    }

  const int nt = K >> 6;
  // prologue: stage tile 0 into buffer 0
  ISSUE(0, 0)
  __syncthreads();                         // full drain + barrier (once)

  int p = 0;
  for (int t = 0; t < nt; ++t) {
    if (t + 1 < nt) {
      const int kt1 = (t + 1) << 6;
      if (p == 0) { ISSUE(1, kt1) } else { ISSUE(0, kt1) }
    }
    if (p == 0) { COMPUTE(0) } else { COMPUTE(1) }
    // prefetch glls had ~compute-length to fly; drain the residue
    asm volatile("s_waitcnt vmcnt(0)" ::: "memory");
    asm volatile("s_waitcnt lgkmcnt(0)" ::: "memory");
    __builtin_amdgcn_s_barrier();
    p ^= 1;
  }
  #undef ISSUE
  #undef COMPUTE

  // ---- epilogue ----  C/D: col=lane&15, row=(lane>>4)*4+reg
  const int rbase = hi * 4;
  if (MODE == 0) {
    #pragma unroll
    for (int mi = 0; mi < 4; ++mi)
      #pragma unroll
      for (int rr = 0; rr < 4; ++rr) {
        int slot = m0 + wm * 64 + mi * 16 + rbase + rr;
        if (slot >= M) continue;
        #pragma unroll
        for (int j = 0; j < 2; ++j) {
          float g = acc[mi][j][rr], u = acc[mi][j + 2][rr];
          float sv = g / (1.f + expf(-g)) * u;
          int col = n0 + wn * 32 + j * 16 + l15;
          outb[(size_t)e * out_estride + (size_t)slot * out_ld + col] = f2bf(sv);
        }
      }
  } else {
    #pragma unroll
    for (int mi = 0; mi < 4; ++mi)
      #pragma unroll
      for (int rr = 0; rr < 4; ++rr) {
        int slot = m0 + wm * 64 + mi * 16 + rbase + rr;
        if (slot >= M) continue;
        unsigned short* row = outb + (size_t)e * out_estride + (size_t)slot * out_ld;
        #pragma unroll
        for (int ni = 0; ni < 4; ++ni)
          row[n0 + bn[ni] + l15] = f2bf(acc[mi][ni][rr]);
      }
  }
}

// ---------------------------------------------------------------- combine ---
// out[t] = sum_k pw[t,k]*y[e_k][slot_k] + y[16][t] + y[17][t]
__global__ __launch_bounds__(256) void combine_k(
    const unsigned short* __restrict__ ybuf, const int* __restrict__ meta,
    const float* __restrict__ pwt, float* __restrict__ out)
{
  const int t = blockIdx.x;
  const int c0 = threadIdx.x * 8;
  float acc[8];
  {
    bf16x8 v0 = *(const bf16x8*)(ybuf + ((size_t)16 * CAP + t) * HID + c0);
    bf16x8 v1 = *(const bf16x8*)(ybuf + ((size_t)17 * CAP + t) * HID + c0);
    #pragma unroll
    for (int j = 0; j < 8; ++j) acc[j] = b2f(v0[j]) + b2f(v1[j]);
  }
  #pragma unroll
  for (int k = 0; k < TOPK; ++k) {
    int m = meta[t * TOPK + k];
    float w = pwt[t * TOPK + k];
    int e = m >> 16, s = m & 0xffff;
    bf16x8 v = *(const bf16x8*)(ybuf + ((size_t)e * CAP + s) * HID + c0);
    #pragma unroll
    for (int j = 0; j < 8; ++j) acc[j] += w * b2f(v[j]);
  }
  float4* o = (float4*)(out + (size_t)t * HID + c0);
  o[0] = make_float4(acc[0], acc[1], acc[2], acc[3]);
  o[1] = make_float4(acc[4], acc[5], acc[6], acc[7]);
}

// --------------------------------------------------------------- launcher ---
extern "C" void kernel_launch(void* const* d_in, const int* in_sizes, int n_in,
                              void* d_out, int out_size, void* d_ws, size_t ws_size,
                              hipStream_t stream) {
  const float* x   = (const float*)d_in[0];
  const float* gw  = (const float*)d_in[1];
  const float* gb  = (const float*)d_in[2];
  const float* wgu = (const float*)d_in[3];
  const float* wd  = (const float*)d_in[4];
  const float* sgu = (const float*)d_in[5];
  const float* sd  = (const float*)d_in[6];
  float* out = (float*)d_out;

  char* ws = (char*)d_ws;
  int*   counts   = (int*)ws;                              // 256 B
  int*   tok_list = (int*)(ws + 256);                      // 64 KB
  int*   meta     = (int*)(ws + 256 + 65536);              // 24 KB
  float* pwt      = (float*)(ws + 256 + 65536 + 24576);    // 24 KB
  unsigned short* x_bf  = (unsigned short*)(ws + 128 * 1024);          // 4 MiB
  unsigned short* act   = x_bf + (size_t)N_TOK * HID;                  // 36 MiB
  unsigned short* ybuf  = act + (size_t)NE2 * CAP * INTER;             // 72 MiB
  unsigned short* wt_gu = ybuf + (size_t)NE2 * CAP * HID;              // 144 MiB
  unsigned short* wt_d  = wt_gu + (size_t)NE2 * HID * 2 * INTER;       // 72 MiB
  const size_t need = (size_t)((char*)(wt_d + (size_t)NE2 * HID * INTER) - ws);
  if (ws_size < need) return;   // ws measured at 1 GiB; need ~328 MiB

  hipMemsetAsync(counts, 0, 256, stream);
  router_k<<<N_TOK, 256, 0, stream>>>(x, gw, gb, counts, tok_list, meta, pwt, x_bf);

  t_gu_k<<<dim3(2 * INTER / 64, HID / 64, NE2), 256, 0, stream>>>(wgu, sgu, wt_gu);
  t_d_k<<<dim3(HID / 64, INTER / 64, NE2), 256, 0, stream>>>(wd, sd, wt_d);

  // gemm1: [18] gather(x)[M,2048] @ wt_gu[e][n][k] -> swiglu -> act[e][M,1024]
  gemm_bf16_k<0><<<dim3(INTER / 64, CAP / 128, NE2), 256, 0, stream>>>(
      x_bf, HID, 0, wt_gu, HID, (size_t)HID * 2 * INTER, counts, tok_list,
      act, INTER, (size_t)CAP * INTER);
  // gemm2: [18] act[e][M,1024] @ wt_d[e][n][k] -> ybuf[e][M,2048] (bf16)
  gemm_bf16_k<1><<<dim3(HID / 128, CAP / 128, NE2), 256, 0, stream>>>(
      act, INTER, (size_t)CAP * INTER, wt_d, INTER, (size_t)HID * INTER, counts, nullptr,
      ybuf, HID, (size_t)CAP * HID);

  combine_k<<<N_TOK, 256, 0, stream>>>(ybuf, meta, pwt, out);
}